// Round 9
// baseline (1656.720 us; speedup 1.0000x reference)
//
#include <hip/hip_runtime.h>

#define CAP 32
#define K 32   // steps per batch; ibuf4 16KB + obuf4 32KB = 48KB LDS

// ---------------------------------------------------------------------------
// Kernel 1: runtime sparsification of W1 (general; for this input nnz=1/row).
// ---------------------------------------------------------------------------
__global__ void sparsify_kernel(const float* __restrict__ W1, int N,
                                int* __restrict__ cnts, int* __restrict__ cols,
                                float* __restrict__ wts) {
  __shared__ int scnt;
  const int row = blockIdx.x;
  if (threadIdx.x == 0) scnt = 0;
  __syncthreads();
  const float* wr = W1 + (long)row * N;
  for (int k = threadIdx.x; k < N; k += blockDim.x) {
    float w = wr[k];
    if (w != 0.0f) {
      int slot = atomicAdd(&scnt, 1);
      if (slot < CAP) {
        cols[row * CAP + slot] = k;
        wts[row * CAP + slot] = w;
      }
    }
  }
  __syncthreads();
  if (threadIdx.x == 0) {
    cnts[row] = scnt;
    if (scnt == 0) { cols[row * CAP] = 0; wts[row * CAP] = 0.0f; }
  }
}

// ---------------------------------------------------------------------------
// Kernel 2: zero rbuf (decode accumulators; replaces decode_dot's launch).
// ---------------------------------------------------------------------------
__global__ void zero_kernel(float* __restrict__ p, int n) {
  int i = blockIdx.x * blockDim.x + threadIdx.x;
  if (i < n) p[i] = 0.0f;
}

// ---------------------------------------------------------------------------
// Kernel 3: producer/consumer, scalar math (R5-validated), b128 LDS traffic.
//   Cadence law (6 experiments): critical-wave time = insts/step x ~5.1 cyc.
//   R5: 19 insts/step -> 333 us. Packed VOP3P (R7/R8) was a wash: equal VALU
//   busy-cycles (compiler movs ate the savings) + worse scheduling. Reverted.
//   This version cuts MEMORY insts only (no mov risk):
//     - I staged as float4 -> ds_read_b128 per 4 steps   (0.25/step)
//     - {vn0,un0,vn1,un1} -> ds_write_b128 per 2 steps   (0.5/step)
//     - 16 scalar VALU (bitwise numpy op order) unchanged
//     => 16.75 insts/step. All LDS at 16B/lane contiguous = 0 conflicts
//     (R7's conflict was 32B stride; R5 measured this pattern at 0).
//   Decode fused into v-writer: r[t] = sum W2[gn]*s (shfl-xor tree + one
//   atomicAdd per t per block). Exact: terms are 20*{0,1}, integer sums
//   < 2^24 are order-independent. decode_dot_kernel deleted.
//   Roles: wave0 compute (zero global ops), wave1 loader+s-writer,
//   wave2 v-writer+decode, wave3 u-writer.
//   Sync = raw s_barrier + lgkmcnt(0) only (stores stay in flight).
// ---------------------------------------------------------------------------
__global__ void __launch_bounds__(256) izh_b128_kernel(
    const float* __restrict__ X, const float* __restrict__ state,
    const float* __restrict__ a, const float* __restrict__ b,
    const float* __restrict__ c, const float* __restrict__ d,
    const float* __restrict__ th, const float* __restrict__ dtv,
    const float* __restrict__ W1, const float* __restrict__ W2,
    const int* __restrict__ cnts, const int* __restrict__ cols,
    const float* __restrict__ wts,
    float* __restrict__ o_s, float* __restrict__ o_st,
    float* __restrict__ rbuf,
    int T, int N)
{
#pragma clang fp contract(off)
  __shared__ __align__(16) float4 ibuf4[2][K / 4][64];  // {I0..I3}      16KB
  __shared__ __align__(16) float4 obuf4[2][K / 2][64];  // {vn0,un0,vn1,un1} 32KB
  __shared__ int s_fast;

  const int wid  = threadIdx.x >> 6;
  const int lane = threadIdx.x & 63;
  const int base = blockIdx.x * 64;
  const int gn   = base + lane;
  const long N2  = 2L * N;
  const int B    = T / K;

  // ---- block-uniform path decision ----
  if (wid == 0) {
    bool elig = (base + 64 <= N);
    if (elig) elig = (cnts[gn] == 1) && (dtv[gn] == 1.0f);
    unsigned long long m = __ballot(elig);
    if (lane == 0) s_fast = (m == ~0ULL) ? 1 : 0;
  }
  __syncthreads();

  if (s_fast) {
    // ---- prologue: loader fills ibuf4[0] (batch 0) ----
    if (wid == 1) {
      const float wn = wts[gn * CAP];
      const int   c0 = cols[gn * CAP];
      const float* Xp = X + c0;
      float xr[K];
#pragma unroll
      for (int i = 0; i < K; ++i) xr[i] = Xp[(size_t)i * N];
#pragma unroll
      for (int q = 0; q < K / 4; ++q) {
        float4 w;
        w.x = wn * xr[4 * q];     w.y = wn * xr[4 * q + 1];
        w.z = wn * xr[4 * q + 2]; w.w = wn * xr[4 * q + 3];
        ibuf4[0][q][lane] = w;
      }
    }
    __syncthreads();   // one-time full sync

    if (wid == 0) {
      // ================= compute wave =================
      float v = state[gn], u = state[N + gn];
      const float bn = b[gn], cn = c[gn], dn = d[gn], thn = th[gn];
      const float Pn = dtv[gn] * a[gn];   // same operands/order as ref's dt*a

      for (int k = 0; k < B; ++k) {
        const int bsel = k & 1;
#pragma unroll
        for (int i = 0; i < K; i += 4) {
          const float4 IV = ibuf4[bsel][i >> 2][lane];  // 1 ds_read_b128
          float vp = 0.f, up = 0.f;
#pragma unroll
          for (int h = 0; h < 4; ++h) {
            const float Ival = (h == 0) ? IV.x : (h == 1) ? IV.y
                             : (h == 2) ? IV.z : IV.w;
            float t1 = 0.04f * v;
            float t2 = t1 * v;
            float t3 = 5.0f * v;
            float t4 = t2 + t3;
            float t5 = t4 + 140.0f;
            float t6 = t5 - u;
            float t7 = t6 + Ival;
            float vn = v + t7;      // dt==1: exact
            float q1 = bn * v;
            float q2 = q1 - u;
            float q3 = Pn * q2;
            float un = u + q3;
            if ((h & 1) == 0) { vp = vn; up = un; }
            else {
              float4 W; W.x = vp; W.y = up; W.z = vn; W.w = un;
              obuf4[bsel][(i + h) >> 1][lane] = W;      // 1 ds_write_b128
            }
            bool sp = vn > thn;     // == (vn-thn)>0 bitwise (IEEE)
            v = sp ? cn : vn;
            u = un + (sp ? dn : 0.0f);
          }
        }
        asm volatile("s_waitcnt lgkmcnt(0)" ::: "memory");
        __builtin_amdgcn_s_barrier();
      }

      // tail (T % K != 0): direct global path (none for T=8192,K=32)
      if (B * K < T) {
        const float w0 = wts[gn * CAP];
        const float* Xp = X + cols[gn * CAP];
        const float w2n = W2[gn];
        for (int t = B * K; t < T; ++t) {
          const float I = w0 * Xp[(size_t)t * N];
          float t1 = 0.04f * v; float t2 = t1 * v; float t3 = 5.0f * v;
          float t4 = t2 + t3; float t5 = t4 + 140.0f; float t6 = t5 - u;
          float t7 = t6 + I; float vn = v + t7;
          float q1 = bn * v; float q2 = q1 - u; float q3 = Pn * q2;
          float un = u + q3;
          bool sp = vn > thn;
          v = sp ? cn : vn; u = un + (sp ? dn : 0.0f);
          float s_ = sp ? 1.0f : 0.0f;
          o_s[(long)t * N + gn] = s_;
          o_st[(long)t * N2 + gn] = v;
          o_st[(long)t * N2 + N + gn] = u;
          float pr = sp ? w2n : 0.0f;
          for (int off = 32; off; off >>= 1) pr += __shfl_xor(pr, off);
          if (lane == 0) atomicAdd(rbuf + t, pr);
        }
      }
    } else if (wid == 1) {
      // ================= loader + s-writer =================
      const float wn = wts[gn * CAP];
      const int   c0 = cols[gn * CAP];
      const float* Xp = X + c0;
      const float thn = th[gn];

      for (int k = 0; k < B; ++k) {
        if (k + 1 < B) {                    // stage I for batch k+1
          float xr[K];
#pragma unroll
          for (int i = 0; i < K; ++i) xr[i] = Xp[(size_t)((k + 1) * K + i) * N];
#pragma unroll
          for (int q = 0; q < K / 4; ++q) {
            float4 w;
            w.x = wn * xr[4 * q];     w.y = wn * xr[4 * q + 1];
            w.z = wn * xr[4 * q + 2]; w.w = wn * xr[4 * q + 3];
            ibuf4[(k + 1) & 1][q][lane] = w;
          }
        }
        if (k > 0) {                        // s-store batch k-1
          const int q = k - 1, bsel = q & 1, t0 = q * K;
#pragma unroll
          for (int p = 0; p < K / 2; ++p) {
            float4 O = obuf4[bsel][p][lane];
            o_s[(size_t)(t0 + 2 * p) * N + gn]     = O.x > thn ? 1.0f : 0.0f;
            o_s[(size_t)(t0 + 2 * p + 1) * N + gn] = O.z > thn ? 1.0f : 0.0f;
          }
        }
        asm volatile("s_waitcnt lgkmcnt(0)" ::: "memory");
        __builtin_amdgcn_s_barrier();
      }
      if (B > 0) {                          // drain batch B-1
        const int q = B - 1, bsel = q & 1, t0 = q * K;
#pragma unroll
        for (int p = 0; p < K / 2; ++p) {
          float4 O = obuf4[bsel][p][lane];
          o_s[(size_t)(t0 + 2 * p) * N + gn]     = O.x > thn ? 1.0f : 0.0f;
          o_s[(size_t)(t0 + 2 * p + 1) * N + gn] = O.z > thn ? 1.0f : 0.0f;
        }
      }
    } else if (wid == 2) {
      // ============ v-writer + decode: v_out = sp?c:vn; r[t] += W2.s ======
      const float thn = th[gn], cn = c[gn], w2n = W2[gn];

      for (int k = 0; k < B; ++k) {
        if (k > 0) {
          const int q = k - 1, bsel = q & 1, t0 = q * K;
#pragma unroll
          for (int p = 0; p < K / 2; ++p) {
            float4 O = obuf4[bsel][p][lane];
            bool sp0 = O.x > thn, sp1 = O.z > thn;
            o_st[(size_t)(t0 + 2 * p) * N2 + gn]     = sp0 ? cn : O.x;
            o_st[(size_t)(t0 + 2 * p + 1) * N2 + gn] = sp1 ? cn : O.z;
            float p0 = sp0 ? w2n : 0.0f;
            float p1 = sp1 ? w2n : 0.0f;
            for (int off = 32; off; off >>= 1) {
              p0 += __shfl_xor(p0, off);
              p1 += __shfl_xor(p1, off);
            }
            if (lane == 0) {
              atomicAdd(rbuf + t0 + 2 * p, p0);
              atomicAdd(rbuf + t0 + 2 * p + 1, p1);
            }
          }
        }
        __builtin_amdgcn_s_barrier();
      }
      if (B > 0) {
        const int q = B - 1, bsel = q & 1, t0 = q * K;
#pragma unroll
        for (int p = 0; p < K / 2; ++p) {
          float4 O = obuf4[bsel][p][lane];
          bool sp0 = O.x > thn, sp1 = O.z > thn;
          o_st[(size_t)(t0 + 2 * p) * N2 + gn]     = sp0 ? cn : O.x;
          o_st[(size_t)(t0 + 2 * p + 1) * N2 + gn] = sp1 ? cn : O.z;
          float p0 = sp0 ? w2n : 0.0f;
          float p1 = sp1 ? w2n : 0.0f;
          for (int off = 32; off; off >>= 1) {
            p0 += __shfl_xor(p0, off);
            p1 += __shfl_xor(p1, off);
          }
          if (lane == 0) {
            atomicAdd(rbuf + t0 + 2 * p, p0);
            atomicAdd(rbuf + t0 + 2 * p + 1, p1);
          }
        }
      }
    } else {
      // ================= u-writer: u_out = un + (sp ? d : 0) =============
      const float thn = th[gn], dn = d[gn];

      for (int k = 0; k < B; ++k) {
        if (k > 0) {
          const int q = k - 1, bsel = q & 1, t0 = q * K;
#pragma unroll
          for (int p = 0; p < K / 2; ++p) {
            float4 O = obuf4[bsel][p][lane];
            o_st[(size_t)(t0 + 2 * p) * N2 + N + gn] =
                O.y + (O.x > thn ? dn : 0.0f);
            o_st[(size_t)(t0 + 2 * p + 1) * N2 + N + gn] =
                O.w + (O.z > thn ? dn : 0.0f);
          }
        }
        __builtin_amdgcn_s_barrier();
      }
      if (B > 0) {
        const int q = B - 1, bsel = q & 1, t0 = q * K;
#pragma unroll
        for (int p = 0; p < K / 2; ++p) {
          float4 O = obuf4[bsel][p][lane];
          o_st[(size_t)(t0 + 2 * p) * N2 + N + gn] =
              O.y + (O.x > thn ? dn : 0.0f);
          o_st[(size_t)(t0 + 2 * p + 1) * N2 + N + gn] =
              O.w + (O.z > thn ? dn : 0.0f);
        }
      }
    }
  } else {
    // ---- general fallback: wave0 threads only, any cnt / dt ----
    if (wid != 0 || gn >= N) return;
    float v = state[gn], u = state[N + gn];
    const float an = a[gn], bn = b[gn], cn = c[gn], dn = d[gn];
    const float thn = th[gn], dtn = dtv[gn];
    const float Pn = dtn * an;
    const float w2n = W2[gn];
    const int cnt = cnts[gn];
    for (int t = 0; t < T; ++t) {
      float I = 0.0f;
      if (cnt <= CAP) {
        for (int j = 0; j < cnt; ++j)
          I = I + wts[gn * CAP + j] * X[(size_t)t * N + cols[gn * CAP + j]];
      } else {
        const float* wr = W1 + (size_t)gn * N;
        const float* xr = X + (size_t)t * N;
        for (int kk = 0; kk < N; ++kk) I = I + wr[kk] * xr[kk];
      }
      float t1 = 0.04f * v; float t2 = t1 * v; float t3 = 5.0f * v;
      float t4 = t2 + t3; float t5 = t4 + 140.0f; float t6 = t5 - u;
      float t7 = t6 + I; float t8 = dtn * t7; float vn = v + t8;
      float q1 = bn * v; float q2 = q1 - u; float q3 = Pn * q2; float un = u + q3;
      float df = vn - thn; bool sp = df > 0.0f;
      v = sp ? cn : vn; u = un + (sp ? dn : 0.0f);
      float s_ = sp ? 1.0f : 0.0f;
      o_s[(size_t)t * N + gn] = s_;
      o_st[(size_t)t * N2 + gn] = v;
      o_st[(size_t)t * N2 + N + gn] = u;
      if (s_ != 0.0f) atomicAdd(rbuf + t, w2n);   // fallback decode (rare)
    }
  }
}

// ---------------------------------------------------------------------------
// Kernel 5: dm[t] = leak*dm[t-1] + r[t], chunked affine scan (1 block, 64 thr)
// ---------------------------------------------------------------------------
__global__ void decode_scan_kernel(const float* __restrict__ r,
                                   const float* __restrict__ leakp,
                                   float* __restrict__ out, int T) {
  __shared__ float Bsh[64], Ssh[64];
  const float leakv = leakp[0];
  const int i = threadIdx.x;                 // 0..63
  const int chunk = (T + 63) / 64;
  const int t0 = i * chunk;
  float B = 0.0f;
  for (int j = 0; j < chunk; ++j) {
    int t = t0 + j;
    if (t < T) B = leakv * B + r[t];
  }
  Bsh[i] = B;
  float A = 1.0f, p = leakv; int e = chunk;
  while (e) { if (e & 1) A *= p; p *= p; e >>= 1; }
  __syncthreads();
  if (i == 0) {
    float dm = 0.0f;
    for (int k = 0; k < 64; ++k) { Ssh[k] = dm; dm = A * dm + Bsh[k]; }
  }
  __syncthreads();
  float dm = Ssh[i];
  for (int j = 0; j < chunk; ++j) {
    int t = t0 + j;
    if (t < T) { dm = leakv * dm + r[t]; out[t] = dm; }
  }
}

// ---------------------------------------------------------------------------
extern "C" void kernel_launch(void* const* d_in, const int* in_sizes, int n_in,
                              void* d_out, int out_size, void* d_ws, size_t ws_size,
                              hipStream_t stream) {
  const float* X  = (const float*)d_in[0];
  const float* st = (const float*)d_in[1];
  const float* W1 = (const float*)d_in[2];
  const float* W2 = (const float*)d_in[3];
  const float* a  = (const float*)d_in[4];
  const float* b  = (const float*)d_in[5];
  const float* c  = (const float*)d_in[6];
  const float* d  = (const float*)d_in[7];
  const float* th = (const float*)d_in[8];
  const float* dt = (const float*)d_in[9];
  const float* lk = (const float*)d_in[10];
  const int N = in_sizes[4];          // a has N elements
  const int T = in_sizes[0] / N;

  float* o_s  = (float*)d_out;               // outputs  [T,N]
  float* o_st = o_s + (long)T * N;           // states   [T,2,N]
  float* o_dm = o_st + 2L * (long)T * N;     // decoded  [T,1]

  int*   cnts = (int*)d_ws;                  // N
  int*   cols = cnts + N;                    // N*CAP
  float* wts  = (float*)(cols + (long)N * CAP); // N*CAP
  float* rbuf = wts + (long)N * CAP;         // T

  sparsify_kernel<<<N, 256, 0, stream>>>(W1, N, cnts, cols, wts);
  zero_kernel<<<(T + 255) / 256, 256, 0, stream>>>(rbuf, T);
  const int nblk = (N + 63) / 64;
  izh_b128_kernel<<<nblk, 256, 0, stream>>>(X, st, a, b, c, d, th, dt, W1, W2,
                                            cnts, cols, wts, o_s, o_st, rbuf,
                                            T, N);
  decode_scan_kernel<<<1, 64, 0, stream>>>(rbuf, lk, o_dm, T);
}

// Round 10
// 513.350 us; speedup vs baseline: 3.2273x; 3.2273x over previous
//
#include <hip/hip_runtime.h>

#define CAP 32
#define K 64   // steps per batch; ibuf2 32KB + obuf 64KB = 96KB LDS

typedef float f32x2 __attribute__((ext_vector_type(2)));

// ---------------------------------------------------------------------------
// Kernel 1: runtime sparsification of W1 (general; for this input nnz=1/row).
// ---------------------------------------------------------------------------
__global__ void sparsify_kernel(const float* __restrict__ W1, int N,
                                int* __restrict__ cnts, int* __restrict__ cols,
                                float* __restrict__ wts) {
  __shared__ int scnt;
  const int row = blockIdx.x;
  if (threadIdx.x == 0) scnt = 0;
  __syncthreads();
  const float* wr = W1 + (long)row * N;
  for (int k = threadIdx.x; k < N; k += blockDim.x) {
    float w = wr[k];
    if (w != 0.0f) {
      int slot = atomicAdd(&scnt, 1);
      if (slot < CAP) {
        cols[row * CAP + slot] = k;
        wts[row * CAP + slot] = w;
      }
    }
  }
  __syncthreads();
  if (threadIdx.x == 0) {
    cnts[row] = scnt;
    if (scnt == 0) { cols[row * CAP] = 0; wts[row * CAP] = 0.0f; }
  }
}

// ---------------------------------------------------------------------------
// Kernel 3: producer/consumer (R5 structure restored; R9's decode fusion and
// scalar-store writers reverted — atomic contention + shfl bank traffic put
// wave2 on the barrier-coupled critical path, 333 -> 1507 us).
//   Deltas vs R5 (each individually proven-safe or bit-provable):
//     - ibuf as f32x2 -> ds_read_b64, 0.5 reads/step (ran conflict-free in
//       R7/R8; R7's conflicts were obuf-layout-only, proven by R8's 0).
//     - K=64: halves barrier/lgkmcnt overhead. LDS 96KB, still 1 block/CU.
//     - u-select: und=un+dn issued off-chain; u = sp?und:un (one chain link
//       shorter after the compare; un provably never -0, so bit-identical).
//   Compute wave/step: 16 VALU + 0.5 ds_read + 2 ds_write_b32 = 18.5 insts
//   (cadence law: ~5.1 cyc/inst on the solo critical wave).
//   Roles: wave0 compute (zero global ops), wave1 loader(I=w*x)+s-writer,
//   wave2 v-writer, wave3 u-writer; writers re-derive spike from vn.
//   Sync = raw s_barrier + lgkmcnt(0) only (writer stores stay in flight).
// ---------------------------------------------------------------------------
__global__ void __launch_bounds__(256) izh_k64_kernel(
    const float* __restrict__ X, const float* __restrict__ state,
    const float* __restrict__ a, const float* __restrict__ b,
    const float* __restrict__ c, const float* __restrict__ d,
    const float* __restrict__ th, const float* __restrict__ dtv,
    const float* __restrict__ W1,
    const int* __restrict__ cnts, const int* __restrict__ cols,
    const float* __restrict__ wts,
    float* __restrict__ o_s, float* __restrict__ o_st,
    int T, int N)
{
#pragma clang fp contract(off)
  __shared__ __align__(16) f32x2 ibuf2[2][K / 2][64];  // staged {I,I'}  32KB
  __shared__ float obuf[2][K][2][64];                  // [buf][step][vn,un][lane] 64KB
  __shared__ int s_fast;

  const int wid  = threadIdx.x >> 6;
  const int lane = threadIdx.x & 63;
  const int base = blockIdx.x * 64;
  const int gn   = base + lane;
  const long N2  = 2L * N;
  const int B    = T / K;

  // ---- block-uniform path decision ----
  if (wid == 0) {
    bool elig = (base + 64 <= N);
    if (elig) elig = (cnts[gn] == 1) && (dtv[gn] == 1.0f);
    unsigned long long m = __ballot(elig);
    if (lane == 0) s_fast = (m == ~0ULL) ? 1 : 0;
  }
  __syncthreads();

  if (s_fast) {
    // ---- prologue: loader fills ibuf2[0] (batch 0) ----
    if (wid == 1) {
      const float wn = wts[gn * CAP];
      const int   c0 = cols[gn * CAP];
      const float* Xp = X + c0;
      float xr[K];
#pragma unroll
      for (int i = 0; i < K; ++i) xr[i] = Xp[(size_t)i * N];
#pragma unroll
      for (int j = 0; j < K / 2; ++j) {
        f32x2 w; w.x = wn * xr[2 * j]; w.y = wn * xr[2 * j + 1];
        ibuf2[0][j][lane] = w;
      }
    }
    __syncthreads();   // one-time full sync

    if (wid == 0) {
      // ================= compute wave =================
      float v = state[gn], u = state[N + gn];
      const float bn = b[gn], cn = c[gn], dn = d[gn], thn = th[gn];
      const float Pn = dtv[gn] * a[gn];   // same operands/order as ref's dt*a

      for (int k = 0; k < B; ++k) {
        const int bsel = k & 1;
#pragma unroll
        for (int i = 0; i < K; i += 2) {
          const f32x2 IV = ibuf2[bsel][i >> 1][lane];  // 1 ds_read_b64/2steps
#pragma unroll
          for (int h = 0; h < 2; ++h) {
            const float Ival = h ? IV.y : IV.x;
            float t1 = 0.04f * v;
            float t2 = t1 * v;
            float t3 = 5.0f * v;
            float t4 = t2 + t3;
            float t5 = t4 + 140.0f;
            float t6 = t5 - u;
            float t7 = t6 + Ival;
            float vn = v + t7;      // dt==1: exact
            float q1 = bn * v;
            float q2 = q1 - u;
            float q3 = Pn * q2;
            float un = u + q3;
            obuf[bsel][i + h][0][lane] = vn;          // ds_write_b32 (free)
            obuf[bsel][i + h][1][lane] = un;          // ds_write_b32 (free)
            float und = un + dn;    // off-chain; un never -0 => bit-safe
            bool sp = vn > thn;     // == (vn-thn)>0 bitwise (IEEE)
            v = sp ? cn : vn;
            u = sp ? und : un;
          }
        }
        asm volatile("s_waitcnt lgkmcnt(0)" ::: "memory");
        __builtin_amdgcn_s_barrier();
      }

      // tail (T % K != 0): direct global path (none for T=8192,K=64)
      if (B * K < T) {
        const float w0 = wts[gn * CAP];
        const float* Xp = X + cols[gn * CAP];
        for (int t = B * K; t < T; ++t) {
          const float I = w0 * Xp[(size_t)t * N];
          float t1 = 0.04f * v; float t2 = t1 * v; float t3 = 5.0f * v;
          float t4 = t2 + t3; float t5 = t4 + 140.0f; float t6 = t5 - u;
          float t7 = t6 + I; float vn = v + t7;
          float q1 = bn * v; float q2 = q1 - u; float q3 = Pn * q2;
          float un = u + q3;
          bool sp = vn > thn;
          v = sp ? cn : vn; u = un + (sp ? dn : 0.0f);
          o_s[(long)t * N + gn] = sp ? 1.0f : 0.0f;
          o_st[(long)t * N2 + gn] = v;
          o_st[(long)t * N2 + N + gn] = u;
        }
      }
    } else if (wid == 1) {
      // ================= loader + s-writer =================
      const float wn = wts[gn * CAP];
      const int   c0 = cols[gn * CAP];
      const float* Xp = X + c0;
      const int r = lane >> 4, j = lane & 15;
      const float4 th4 = *(const float4*)&th[base + 4 * j];

      for (int k = 0; k < B; ++k) {
        if (k + 1 < B) {                    // stage I for batch k+1
          float xr[K];
#pragma unroll
          for (int i = 0; i < K; ++i) xr[i] = Xp[(size_t)((k + 1) * K + i) * N];
#pragma unroll
          for (int jj = 0; jj < K / 2; ++jj) {
            f32x2 w; w.x = wn * xr[2 * jj]; w.y = wn * xr[2 * jj + 1];
            ibuf2[(k + 1) & 1][jj][lane] = w;
          }
        }
        if (k > 0) {                        // s-store batch k-1
          const int q = k - 1, bsel = q & 1, t0 = q * K;
#pragma unroll
          for (int i = 0; i < K; i += 4) {
            float4 vn4 = *(const float4*)&obuf[bsel][i + r][0][4 * j];
            float4 s4;
            s4.x = vn4.x > th4.x ? 1.0f : 0.0f;
            s4.y = vn4.y > th4.y ? 1.0f : 0.0f;
            s4.z = vn4.z > th4.z ? 1.0f : 0.0f;
            s4.w = vn4.w > th4.w ? 1.0f : 0.0f;
            *(float4*)(o_s + (size_t)(t0 + i + r) * N + base + 4 * j) = s4;
          }
        }
        asm volatile("s_waitcnt lgkmcnt(0)" ::: "memory");
        __builtin_amdgcn_s_barrier();
      }
      if (B > 0) {                          // drain batch B-1
        const int q = B - 1, bsel = q & 1, t0 = q * K;
#pragma unroll
        for (int i = 0; i < K; i += 4) {
          float4 vn4 = *(const float4*)&obuf[bsel][i + r][0][4 * j];
          float4 s4;
          s4.x = vn4.x > th4.x ? 1.0f : 0.0f;
          s4.y = vn4.y > th4.y ? 1.0f : 0.0f;
          s4.z = vn4.z > th4.z ? 1.0f : 0.0f;
          s4.w = vn4.w > th4.w ? 1.0f : 0.0f;
          *(float4*)(o_s + (size_t)(t0 + i + r) * N + base + 4 * j) = s4;
        }
      }
    } else if (wid == 2) {
      // ================= v-writer: v_out = sp ? c : vn =================
      const int r = lane >> 4, j = lane & 15;
      const float4 th4 = *(const float4*)&th[base + 4 * j];
      const float4 c4  = *(const float4*)&c[base + 4 * j];

      for (int k = 0; k < B; ++k) {
        if (k > 0) {
          const int q = k - 1, bsel = q & 1, t0 = q * K;
#pragma unroll
          for (int i = 0; i < K; i += 4) {
            float4 vn4 = *(const float4*)&obuf[bsel][i + r][0][4 * j];
            float4 o4;
            o4.x = vn4.x > th4.x ? c4.x : vn4.x;
            o4.y = vn4.y > th4.y ? c4.y : vn4.y;
            o4.z = vn4.z > th4.z ? c4.z : vn4.z;
            o4.w = vn4.w > th4.w ? c4.w : vn4.w;
            *(float4*)(o_st + (size_t)(t0 + i + r) * N2 + base + 4 * j) = o4;
          }
        }
        __builtin_amdgcn_s_barrier();
      }
      if (B > 0) {
        const int q = B - 1, bsel = q & 1, t0 = q * K;
#pragma unroll
        for (int i = 0; i < K; i += 4) {
          float4 vn4 = *(const float4*)&obuf[bsel][i + r][0][4 * j];
          float4 o4;
          o4.x = vn4.x > th4.x ? c4.x : vn4.x;
          o4.y = vn4.y > th4.y ? c4.y : vn4.y;
          o4.z = vn4.z > th4.z ? c4.z : vn4.z;
          o4.w = vn4.w > th4.w ? c4.w : vn4.w;
          *(float4*)(o_st + (size_t)(t0 + i + r) * N2 + base + 4 * j) = o4;
        }
      }
    } else {
      // ================= u-writer: u_out = un + (sp ? d : 0) =============
      const int r = lane >> 4, j = lane & 15;
      const float4 th4 = *(const float4*)&th[base + 4 * j];
      const float4 d4  = *(const float4*)&d[base + 4 * j];

      for (int k = 0; k < B; ++k) {
        if (k > 0) {
          const int q = k - 1, bsel = q & 1, t0 = q * K;
#pragma unroll
          for (int i = 0; i < K; i += 4) {
            float4 vn4 = *(const float4*)&obuf[bsel][i + r][0][4 * j];
            float4 un4 = *(const float4*)&obuf[bsel][i + r][1][4 * j];
            float4 o4;
            o4.x = un4.x + (vn4.x > th4.x ? d4.x : 0.0f);
            o4.y = un4.y + (vn4.y > th4.y ? d4.y : 0.0f);
            o4.z = un4.z + (vn4.z > th4.z ? d4.z : 0.0f);
            o4.w = un4.w + (vn4.w > th4.w ? d4.w : 0.0f);
            *(float4*)(o_st + (size_t)(t0 + i + r) * N2 + N + base + 4 * j) = o4;
          }
        }
        __builtin_amdgcn_s_barrier();
      }
      if (B > 0) {
        const int q = B - 1, bsel = q & 1, t0 = q * K;
#pragma unroll
        for (int i = 0; i < K; i += 4) {
          float4 vn4 = *(const float4*)&obuf[bsel][i + r][0][4 * j];
          float4 un4 = *(const float4*)&obuf[bsel][i + r][1][4 * j];
          float4 o4;
          o4.x = un4.x + (vn4.x > th4.x ? d4.x : 0.0f);
          o4.y = un4.y + (vn4.y > th4.y ? d4.y : 0.0f);
          o4.z = un4.z + (vn4.z > th4.z ? d4.z : 0.0f);
          o4.w = un4.w + (vn4.w > th4.w ? d4.w : 0.0f);
          *(float4*)(o_st + (size_t)(t0 + i + r) * N2 + N + base + 4 * j) = o4;
        }
      }
    }
  } else {
    // ---- general fallback: wave0 threads only, any cnt / dt ----
    if (wid != 0 || gn >= N) return;
    float v = state[gn], u = state[N + gn];
    const float an = a[gn], bn = b[gn], cn = c[gn], dn = d[gn];
    const float thn = th[gn], dtn = dtv[gn];
    const float Pn = dtn * an;
    const int cnt = cnts[gn];
    for (int t = 0; t < T; ++t) {
      float I = 0.0f;
      if (cnt <= CAP) {
        for (int j = 0; j < cnt; ++j)
          I = I + wts[gn * CAP + j] * X[(size_t)t * N + cols[gn * CAP + j]];
      } else {
        const float* wr = W1 + (size_t)gn * N;
        const float* xr = X + (size_t)t * N;
        for (int kk = 0; kk < N; ++kk) I = I + wr[kk] * xr[kk];
      }
      float t1 = 0.04f * v; float t2 = t1 * v; float t3 = 5.0f * v;
      float t4 = t2 + t3; float t5 = t4 + 140.0f; float t6 = t5 - u;
      float t7 = t6 + I; float t8 = dtn * t7; float vn = v + t8;
      float q1 = bn * v; float q2 = q1 - u; float q3 = Pn * q2; float un = u + q3;
      float df = vn - thn; bool sp = df > 0.0f;
      v = sp ? cn : vn; u = un + (sp ? dn : 0.0f);
      o_s[(size_t)t * N + gn] = sp ? 1.0f : 0.0f;
      o_st[(size_t)t * N2 + gn] = v;
      o_st[(size_t)t * N2 + N + gn] = u;
    }
  }
}

// ---------------------------------------------------------------------------
// Kernel 4: r[t] = W2 @ s[t], grid-stride over t (exact: terms are 20*{0,1},
// integer sums < 2^24 are order-independent).
// ---------------------------------------------------------------------------
__global__ void decode_dot_kernel(const float* __restrict__ o_s,
                                  const float* __restrict__ W2,
                                  float* __restrict__ r, int T, int N) {
  __shared__ float red[4];
  for (int t = blockIdx.x; t < T; t += gridDim.x) {
    const float* srow = o_s + (long)t * N;
    float p = 0.0f;
    for (int n = threadIdx.x; n < N; n += blockDim.x)
      p += W2[n] * srow[n];
    for (int off = 32; off > 0; off >>= 1) p += __shfl_down(p, off);
    if ((threadIdx.x & 63) == 0) red[threadIdx.x >> 6] = p;
    __syncthreads();
    if (threadIdx.x == 0) {
      float tot = 0.f;
      const int nw = blockDim.x >> 6;
      for (int w = 0; w < nw; ++w) tot += red[w];
      r[t] = tot;
    }
    __syncthreads();
  }
}

// ---------------------------------------------------------------------------
// Kernel 5: dm[t] = leak*dm[t-1] + r[t], chunked affine scan (1 block, 64 thr)
// ---------------------------------------------------------------------------
__global__ void decode_scan_kernel(const float* __restrict__ r,
                                   const float* __restrict__ leakp,
                                   float* __restrict__ out, int T) {
  __shared__ float Bsh[64], Ssh[64];
  const float leakv = leakp[0];
  const int i = threadIdx.x;                 // 0..63
  const int chunk = (T + 63) / 64;
  const int t0 = i * chunk;
  float B = 0.0f;
  for (int j = 0; j < chunk; ++j) {
    int t = t0 + j;
    if (t < T) B = leakv * B + r[t];
  }
  Bsh[i] = B;
  float A = 1.0f, p = leakv; int e = chunk;
  while (e) { if (e & 1) A *= p; p *= p; e >>= 1; }
  __syncthreads();
  if (i == 0) {
    float dm = 0.0f;
    for (int k = 0; k < 64; ++k) { Ssh[k] = dm; dm = A * dm + Bsh[k]; }
  }
  __syncthreads();
  float dm = Ssh[i];
  for (int j = 0; j < chunk; ++j) {
    int t = t0 + j;
    if (t < T) { dm = leakv * dm + r[t]; out[t] = dm; }
  }
}

// ---------------------------------------------------------------------------
extern "C" void kernel_launch(void* const* d_in, const int* in_sizes, int n_in,
                              void* d_out, int out_size, void* d_ws, size_t ws_size,
                              hipStream_t stream) {
  const float* X  = (const float*)d_in[0];
  const float* st = (const float*)d_in[1];
  const float* W1 = (const float*)d_in[2];
  const float* W2 = (const float*)d_in[3];
  const float* a  = (const float*)d_in[4];
  const float* b  = (const float*)d_in[5];
  const float* c  = (const float*)d_in[6];
  const float* d  = (const float*)d_in[7];
  const float* th = (const float*)d_in[8];
  const float* dt = (const float*)d_in[9];
  const float* lk = (const float*)d_in[10];
  const int N = in_sizes[4];          // a has N elements
  const int T = in_sizes[0] / N;

  float* o_s  = (float*)d_out;               // outputs  [T,N]
  float* o_st = o_s + (long)T * N;           // states   [T,2,N]
  float* o_dm = o_st + 2L * (long)T * N;     // decoded  [T,1]

  int*   cnts = (int*)d_ws;                  // N
  int*   cols = cnts + N;                    // N*CAP
  float* wts  = (float*)(cols + (long)N * CAP); // N*CAP
  float* rbuf = wts + (long)N * CAP;         // T

  sparsify_kernel<<<N, 256, 0, stream>>>(W1, N, cnts, cols, wts);
  const int nblk = (N + 63) / 64;
  izh_k64_kernel<<<nblk, 256, 0, stream>>>(X, st, a, b, c, d, th, dt, W1,
                                           cnts, cols, wts, o_s, o_st, T, N);
  const int ndec = (T < 2048) ? T : 2048;
  decode_dot_kernel<<<ndec, 256, 0, stream>>>(o_s, W2, rbuf, T, N);
  decode_scan_kernel<<<1, 64, 0, stream>>>(rbuf, lk, o_dm, T);
}